// Round 4
// baseline (4242.444 us; speedup 1.0000x reference)
//
#include <hip/hip_runtime.h>
#include <math.h>

#define NN 20000
#define NE 320000
#define ET 32          // edges per chunk
#define ST 132         // LDS row stride in floats
#define GN 4           // rec-nodes owned per edge-block

__device__ __forceinline__ float frelu(float x){ return fmaxf(x, 0.f); }

// ---------------- histograms: degS over send (normalization), cntR over rec (CSR) ----------------
__global__ void k_hist(const int* __restrict__ eidx, int* __restrict__ degS,
                       int* __restrict__ cntR, int mode){
  int t = blockIdx.x*256 + threadIdx.x;
  if(t < NE){
    atomicAdd(&degS[eidx[t]], 1);
    if(mode) atomicAdd(&cntR[eidx[NE+t]], 1);
  }
}

// ---------------- exclusive scan of cntR -> off[N+1], cur[N] (single block) ----------------
__global__ __launch_bounds__(256) void k_scan(const int* __restrict__ cntR,
                                              int* __restrict__ off, int* __restrict__ cur){
  __shared__ int part[256];
  __shared__ int pre[256];
  const int t = threadIdx.x;
  const int start = t*80, end = min(start+80, NN);
  int sm = 0;
  for(int n=start;n<end;n++) sm += cntR[n];
  part[t] = sm;
  __syncthreads();
  if(t==0){ int r=0; for(int i=0;i<256;i++){ pre[i]=r; r+=part[i]; } }
  __syncthreads();
  int run = pre[t];
  for(int n=start;n<end;n++){ off[n]=run; cur[n]=run; run += cntR[n]; }
  if(end==NN && start<=NN) off[NN]=run;
}

// ---------------- scatter edge ids into rec-sorted order ----------------
__global__ void k_fill(const int* __restrict__ eidx, int* __restrict__ cur,
                       int* __restrict__ eord){
  int e = blockIdx.x*256 + threadIdx.x;
  if(e < NE){
    int r = eidx[NE+e];
    int p = atomicAdd(&cur[r], 1);
    eord[p] = e;
  }
}

// ---------------- per-node precompute: A = s@W1[0:128], B = s@W1[128:256] ----------------
__global__ __launch_bounds__(256) void k_ab(const float* __restrict__ s,
                                            const float* __restrict__ W1,
                                            float* __restrict__ A,
                                            float* __restrict__ B){
  __shared__ float sx[8*128];
  const int nb = blockIdx.x*8;
  for(int i=threadIdx.x; i<8*128; i+=256) sx[i] = s[(size_t)nb*128 + i];
  __syncthreads();
  const int col = threadIdx.x;
  const int j = col & 127;
  const float* w = W1 + (col < 128 ? 0 : 128*128) + j;
  float acc[8];
  #pragma unroll
  for(int n=0;n<8;n++) acc[n]=0.f;
  for(int k=0;k<128;k++){
    float wv = w[(size_t)k*128];
    #pragma unroll
    for(int n=0;n<8;n++) acc[n] += sx[n*128+k]*wv;
  }
  float* dst = (col<128 ? A : B) + (size_t)nb*8*16 + j;   // (nb*128)
  #pragma unroll
  for(int n=0;n<8;n++) dst[(size_t)n*128] = acc[n];
}

// ======================= CSR-owned edge kernel: zero float atomics =======================
// Block owns nodes [nb, nb+GN); processes its rec-sorted edges in chunks of ET.
// Register accumulators: t<128 -> m col j=t (4 nodes); t>=128 -> pos_m col j=t-128.
// __launch_bounds__(256,4): cap VGPR at 128 (R2 post-mortem: unbounded alloc hit 256 + scratch spills).
__global__ __launch_bounds__(256, 4) void k_edge2(
    const float* __restrict__ v, const int* __restrict__ eidx,
    const float* __restrict__ Wvw, const float* __restrict__ Wvb,
    const float* __restrict__ W1c, const float* __restrict__ b1,
    const float* __restrict__ W2,  const float* __restrict__ b2,
    const float* __restrict__ pW1, const float* __restrict__ pb1,
    const float* __restrict__ pW2, const float* __restrict__ pb2,
    const float* __restrict__ A,   const float* __restrict__ Bn,
    const int* __restrict__ off,   const int* __restrict__ eord,
    float* __restrict__ Magg, float* __restrict__ Pagg)
{
  __shared__ float B0[ET*ST];   // d -> m
  __shared__ float Bv[ET*ST];   // v_ij
  __shared__ float B2[ET*ST];   // h -> q -> pos_m
  __shared__ float sEP[ET*16];  // edge_attr, then pm
  __shared__ int sS[ET], sR[ET];
  const int t  = threadIdx.x;
  const int nb = blockIdx.x*GN;
  const int eBeg = off[nb], eEnd = off[nb+GN];
  const int jcol = t&127;
  const bool isP = (t>=128);
  float acc4[GN];
  #pragma unroll
  for(int ln=0;ln<GN;ln++) acc4[ln]=0.f;

  #pragma clang loop unroll(disable)
  for(int base=eBeg; base<eEnd; base+=ET){
    const int ce = min(ET, eEnd-base);
    if(t<ET){
      if(t<ce){ int e=eord[base+t]; sS[t]=eidx[e]; sR[t]=eidx[NE+e]; }
      else    { sS[t]=nb; sR[t]=nb; }
    }
    __syncthreads();

    // Ph1: d = v[rec] - v[send]
    {
      const int e = t>>3, q = t&7;
      const float4* vs = (const float4*)(v + (size_t)sS[e]*128);
      const float4* vr = (const float4*)(v + (size_t)sR[e]*128);
      #pragma unroll
      for(int i=0;i<4;i++){
        int f = q + i*8;
        float4 a = vr[f], b = vs[f];
        *(float4*)(B0 + e*ST + f*4) = make_float4(a.x-b.x, a.y-b.y, a.z-b.z, a.w-b.w);
      }
    }
    __syncthreads();

    // Ph2: v_ij = mv_linear(d, Wv) ; edge_attr = sum_b v_ij^2
    {
      const int e = t>>3, q = t&7;
      float a0[8], a1[8];
      #pragma unroll
      for(int b=0;b<8;b++){a0[b]=0.f;a1[b]=0.f;}
      a0[0]=Wvb[q]; a1[0]=Wvb[q+8];
      const float* dp = B0 + e*ST;
      #pragma unroll
      for(int c=0;c<16;c++){
        float4 da=*(const float4*)(dp + c*8);
        float4 db=*(const float4*)(dp + c*8 + 4);
        float4 g0=*(const float4*)(Wvw + (q*16+c)*4);
        float4 g1=*(const float4*)(Wvw + ((q+8)*16+c)*4);
        a0[0]+=da.x*g0.x; a0[1]+=da.y*g0.y; a0[2]+=da.z*g0.y; a0[3]+=da.w*g0.y;
        a0[4]+=db.x*g0.z; a0[5]+=db.y*g0.z; a0[6]+=db.z*g0.z; a0[7]+=db.w*g0.w;
        a1[0]+=da.x*g1.x; a1[1]+=da.y*g1.y; a1[2]+=da.z*g1.y; a1[3]+=da.w*g1.y;
        a1[4]+=db.x*g1.z; a1[5]+=db.y*g1.z; a1[6]+=db.z*g1.z; a1[7]+=db.w*g1.w;
      }
      *(float4*)(Bv + e*ST + q*8)       = make_float4(a0[0],a0[1],a0[2],a0[3]);
      *(float4*)(Bv + e*ST + q*8 + 4)   = make_float4(a0[4],a0[5],a0[6],a0[7]);
      *(float4*)(Bv + e*ST + (q+8)*8)   = make_float4(a1[0],a1[1],a1[2],a1[3]);
      *(float4*)(Bv + e*ST + (q+8)*8+4) = make_float4(a1[4],a1[5],a1[6],a1[7]);
      float e0s=0.f, e1s=0.f;
      #pragma unroll
      for(int b=0;b<8;b++){ e0s+=a0[b]*a0[b]; e1s+=a1[b]*a1[b]; }
      sEP[e*16+q]=e0s; sEP[e*16+q+8]=e1s;
    }
    __syncthreads();

    // Ph3: h = relu(A[send] + B[rec] + ea@W1c + b1)
    {
      const int j = t&127, eg = t>>7;
      float w1c[16];
      #pragma unroll
      for(int c=0;c<16;c++) w1c[c]=W1c[(size_t)c*128 + j];
      const float bb = b1[j];
      for(int ei=0; ei<16; ei++){
        const int e = eg*16 + ei;
        float acc = A[(size_t)sS[e]*128 + j] + Bn[(size_t)sR[e]*128 + j] + bb;
        #pragma unroll
        for(int c=0;c<16;c++) acc += sEP[e*16+c]*w1c[c];
        B2[e*ST + j] = frelu(acc);
      }
    }
    __syncthreads();

    // Ph4: m = h@W2 + b2 -> B0
    {
      const int jq = t&31, eg = t>>5;
      const int j0 = jq*4;
      float4 bb = *(const float4*)(b2 + j0);
      float acc[4][4];
      #pragma unroll
      for(int a=0;a<4;a++){ acc[a][0]=bb.x; acc[a][1]=bb.y; acc[a][2]=bb.z; acc[a][3]=bb.w; }
      for(int k=0;k<128;k+=4){
        float4 w0=*(const float4*)(W2 + (size_t)(k+0)*128 + j0);
        float4 w1=*(const float4*)(W2 + (size_t)(k+1)*128 + j0);
        float4 w2=*(const float4*)(W2 + (size_t)(k+2)*128 + j0);
        float4 w3=*(const float4*)(W2 + (size_t)(k+3)*128 + j0);
        #pragma unroll
        for(int a=0;a<4;a++){
          float4 h4=*(const float4*)(B2 + (eg*4+a)*ST + k);
          acc[a][0] += h4.x*w0.x + h4.y*w1.x + h4.z*w2.x + h4.w*w3.x;
          acc[a][1] += h4.x*w0.y + h4.y*w1.y + h4.z*w2.y + h4.w*w3.y;
          acc[a][2] += h4.x*w0.z + h4.y*w1.z + h4.z*w2.z + h4.w*w3.z;
          acc[a][3] += h4.x*w0.w + h4.y*w1.w + h4.z*w2.w + h4.w*w3.w;
        }
      }
      #pragma unroll
      for(int a=0;a<4;a++){
        const int e = eg*4+a;
        *(float4*)(B0 + e*ST + j0) = make_float4(acc[a][0],acc[a][1],acc[a][2],acc[a][3]);
      }
    }
    __syncthreads();

    // Ph5: q = relu(m@pW1 + pb1) -> B2
    {
      const int jq = t&31, eg = t>>5;
      const int j0 = jq*4;
      float4 bb = *(const float4*)(pb1 + j0);
      float acc[4][4];
      #pragma unroll
      for(int a=0;a<4;a++){ acc[a][0]=bb.x; acc[a][1]=bb.y; acc[a][2]=bb.z; acc[a][3]=bb.w; }
      for(int k=0;k<128;k+=4){
        float4 w0=*(const float4*)(pW1 + (size_t)(k+0)*128 + j0);
        float4 w1=*(const float4*)(pW1 + (size_t)(k+1)*128 + j0);
        float4 w2=*(const float4*)(pW1 + (size_t)(k+2)*128 + j0);
        float4 w3=*(const float4*)(pW1 + (size_t)(k+3)*128 + j0);
        #pragma unroll
        for(int a=0;a<4;a++){
          float4 m4=*(const float4*)(B0 + (eg*4+a)*ST + k);
          acc[a][0] += m4.x*w0.x + m4.y*w1.x + m4.z*w2.x + m4.w*w3.x;
          acc[a][1] += m4.x*w0.y + m4.y*w1.y + m4.z*w2.y + m4.w*w3.y;
          acc[a][2] += m4.x*w0.z + m4.y*w1.z + m4.z*w2.z + m4.w*w3.z;
          acc[a][3] += m4.x*w0.w + m4.y*w1.w + m4.z*w2.w + m4.w*w3.w;
        }
      }
      #pragma unroll
      for(int a=0;a<4;a++){
        const int e = eg*4+a;
        *(float4*)(B2 + e*ST + j0) = make_float4(frelu(acc[a][0]),frelu(acc[a][1]),frelu(acc[a][2]),frelu(acc[a][3]));
      }
    }
    __syncthreads();

    // Ph6: pm = q@pW2 + pb2 -> sEP
    {
      const int e = t>>3, jq = t&7;
      float acc0 = pb2[jq], acc1 = pb2[jq+8];
      const float* qp = B2 + e*ST;
      for(int k=0;k<128;k+=4){
        float4 q4 = *(const float4*)(qp + k);
        acc0 += q4.x*pW2[(k+0)*16+jq]   + q4.y*pW2[(k+1)*16+jq]   + q4.z*pW2[(k+2)*16+jq]   + q4.w*pW2[(k+3)*16+jq];
        acc1 += q4.x*pW2[(k+0)*16+jq+8] + q4.y*pW2[(k+1)*16+jq+8] + q4.z*pW2[(k+2)*16+jq+8] + q4.w*pW2[(k+3)*16+jq+8];
      }
      sEP[e*16+jq]=acc0; sEP[e*16+jq+8]=acc1;
    }
    __syncthreads();

    // Ph7: pos_m = v_ij * pm -> B2 (q is dead)
    {
      const int e = t>>3, q = t&7;
      #pragma unroll
      for(int i=0;i<4;i++){
        int f = q + i*8;
        float4 vv = *(const float4*)(Bv + e*ST + f*4);
        float pmv = sEP[e*16 + (f>>1)];
        *(float4*)(B2 + e*ST + f*4) = make_float4(vv.x*pmv, vv.y*pmv, vv.z*pmv, vv.w*pmv);
      }
    }
    __syncthreads();

    // Ph8: segmented accumulation into registers (edges are rec-local: sR[e]-nb in [0,GN))
    {
      const float* src = isP ? B2 : B0;
      for(int e=0;e<ce;e++){
        const int ln = sR[e]-nb;          // LDS broadcast
        const float val = src[e*ST + jcol];
        #pragma unroll
        for(int k=0;k<GN;k++) acc4[k] += (ln==k)? val : 0.f;
      }
    }
    __syncthreads();   // protect LDS reuse next chunk
  }

  // write 8 coalesced rows (raw sums; k_node applies 1/sqrt(deg))
  float* dst = isP ? Pagg : Magg;
  #pragma unroll
  for(int ln=0;ln<GN;ln++)
    dst[(size_t)(nb+ln)*128 + jcol] = acc4[ln];
}

// ---------------- fallback atomic edge kernel (R0 path) ----------------
__global__ __launch_bounds__(256) void k_edge0(
    const float* __restrict__ v, const int* __restrict__ eidx,
    const float* __restrict__ Wvw, const float* __restrict__ Wvb,
    const float* __restrict__ W1c, const float* __restrict__ b1,
    const float* __restrict__ W2,  const float* __restrict__ b2,
    const float* __restrict__ pW1, const float* __restrict__ pb1,
    const float* __restrict__ pW2, const float* __restrict__ pb2,
    const float* __restrict__ A,   const float* __restrict__ Bn,
    float* __restrict__ mOut, float* __restrict__ pOut)
{
  __shared__ float B0[ET*ST];
  __shared__ float Bv[ET*ST];
  __shared__ float B2[ET*ST];
  __shared__ float sEP[ET*16];
  __shared__ int sS[ET], sR[ET];
  const int t  = threadIdx.x;
  const int e0 = blockIdx.x * ET;
  if(t<ET){ sS[t]=eidx[e0+t]; sR[t]=eidx[NE+e0+t]; }
  __syncthreads();
  {
    const int e = t>>3, q = t&7;
    const float4* vs = (const float4*)(v + (size_t)sS[e]*128);
    const float4* vr = (const float4*)(v + (size_t)sR[e]*128);
    #pragma unroll
    for(int i=0;i<4;i++){
      int f = q + i*8;
      float4 a = vr[f], b = vs[f];
      *(float4*)(B0 + e*ST + f*4) = make_float4(a.x-b.x, a.y-b.y, a.z-b.z, a.w-b.w);
    }
  }
  __syncthreads();
  {
    const int e = t>>3, q = t&7;
    float a0[8], a1[8];
    #pragma unroll
    for(int b=0;b<8;b++){a0[b]=0.f;a1[b]=0.f;}
    a0[0]=Wvb[q]; a1[0]=Wvb[q+8];
    const float* dp = B0 + e*ST;
    #pragma unroll
    for(int c=0;c<16;c++){
      float4 da=*(const float4*)(dp + c*8);
      float4 db=*(const float4*)(dp + c*8 + 4);
      float4 g0=*(const float4*)(Wvw + (q*16+c)*4);
      float4 g1=*(const float4*)(Wvw + ((q+8)*16+c)*4);
      a0[0]+=da.x*g0.x; a0[1]+=da.y*g0.y; a0[2]+=da.z*g0.y; a0[3]+=da.w*g0.y;
      a0[4]+=db.x*g0.z; a0[5]+=db.y*g0.z; a0[6]+=db.z*g0.z; a0[7]+=db.w*g0.w;
      a1[0]+=da.x*g1.x; a1[1]+=da.y*g1.y; a1[2]+=da.z*g1.y; a1[3]+=da.w*g1.y;
      a1[4]+=db.x*g1.z; a1[5]+=db.y*g1.z; a1[6]+=db.z*g1.z; a1[7]+=db.w*g1.w;
    }
    *(float4*)(Bv + e*ST + q*8)       = make_float4(a0[0],a0[1],a0[2],a0[3]);
    *(float4*)(Bv + e*ST + q*8 + 4)   = make_float4(a0[4],a0[5],a0[6],a0[7]);
    *(float4*)(Bv + e*ST + (q+8)*8)   = make_float4(a1[0],a1[1],a1[2],a1[3]);
    *(float4*)(Bv + e*ST + (q+8)*8+4) = make_float4(a1[4],a1[5],a1[6],a1[7]);
    float e0s=0.f, e1s=0.f;
    #pragma unroll
    for(int b=0;b<8;b++){ e0s+=a0[b]*a0[b]; e1s+=a1[b]*a1[b]; }
    sEP[e*16+q]=e0s; sEP[e*16+q+8]=e1s;
  }
  __syncthreads();
  {
    const int j = t&127, eg = t>>7;
    float w1c[16];
    #pragma unroll
    for(int c=0;c<16;c++) w1c[c]=W1c[(size_t)c*128 + j];
    const float bb = b1[j];
    for(int ei=0; ei<16; ei++){
      const int e = eg*16 + ei;
      float acc = A[(size_t)sS[e]*128 + j] + Bn[(size_t)sR[e]*128 + j] + bb;
      #pragma unroll
      for(int c=0;c<16;c++) acc += sEP[e*16+c]*w1c[c];
      B2[e*ST + j] = frelu(acc);
    }
  }
  __syncthreads();
  {
    const int jq = t&31, eg = t>>5;
    const int j0 = jq*4;
    float4 bb = *(const float4*)(b2 + j0);
    float acc[4][4];
    #pragma unroll
    for(int a=0;a<4;a++){ acc[a][0]=bb.x; acc[a][1]=bb.y; acc[a][2]=bb.z; acc[a][3]=bb.w; }
    for(int k=0;k<128;k+=4){
      float4 w0=*(const float4*)(W2 + (size_t)(k+0)*128 + j0);
      float4 w1=*(const float4*)(W2 + (size_t)(k+1)*128 + j0);
      float4 w2=*(const float4*)(W2 + (size_t)(k+2)*128 + j0);
      float4 w3=*(const float4*)(W2 + (size_t)(k+3)*128 + j0);
      #pragma unroll
      for(int a=0;a<4;a++){
        float4 h4=*(const float4*)(B2 + (eg*4+a)*ST + k);
        acc[a][0] += h4.x*w0.x + h4.y*w1.x + h4.z*w2.x + h4.w*w3.x;
        acc[a][1] += h4.x*w0.y + h4.y*w1.y + h4.z*w2.y + h4.w*w3.y;
        acc[a][2] += h4.x*w0.z + h4.y*w1.z + h4.z*w2.z + h4.w*w3.z;
        acc[a][3] += h4.x*w0.w + h4.y*w1.w + h4.z*w2.w + h4.w*w3.w;
      }
    }
    #pragma unroll
    for(int a=0;a<4;a++){
      const int e = eg*4+a;
      *(float4*)(B0 + e*ST + j0) = make_float4(acc[a][0],acc[a][1],acc[a][2],acc[a][3]);
      float* mg = mOut + (size_t)sR[e]*128 + j0;
      atomicAdd(mg+0, acc[a][0]); atomicAdd(mg+1, acc[a][1]);
      atomicAdd(mg+2, acc[a][2]); atomicAdd(mg+3, acc[a][3]);
    }
  }
  __syncthreads();
  {
    const int jq = t&31, eg = t>>5;
    const int j0 = jq*4;
    float4 bb = *(const float4*)(pb1 + j0);
    float acc[4][4];
    #pragma unroll
    for(int a=0;a<4;a++){ acc[a][0]=bb.x; acc[a][1]=bb.y; acc[a][2]=bb.z; acc[a][3]=bb.w; }
    for(int k=0;k<128;k+=4){
      float4 w0=*(const float4*)(pW1 + (size_t)(k+0)*128 + j0);
      float4 w1=*(const float4*)(pW1 + (size_t)(k+1)*128 + j0);
      float4 w2=*(const float4*)(pW1 + (size_t)(k+2)*128 + j0);
      float4 w3=*(const float4*)(pW1 + (size_t)(k+3)*128 + j0);
      #pragma unroll
      for(int a=0;a<4;a++){
        float4 m4=*(const float4*)(B0 + (eg*4+a)*ST + k);
        acc[a][0] += m4.x*w0.x + m4.y*w1.x + m4.z*w2.x + m4.w*w3.x;
        acc[a][1] += m4.x*w0.y + m4.y*w1.y + m4.z*w2.y + m4.w*w3.y;
        acc[a][2] += m4.x*w0.z + m4.y*w1.z + m4.z*w2.z + m4.w*w3.z;
        acc[a][3] += m4.x*w0.w + m4.y*w1.w + m4.z*w2.w + m4.w*w3.w;
      }
    }
    #pragma unroll
    for(int a=0;a<4;a++){
      const int e = eg*4+a;
      *(float4*)(B2 + e*ST + j0) = make_float4(frelu(acc[a][0]),frelu(acc[a][1]),frelu(acc[a][2]),frelu(acc[a][3]));
    }
  }
  __syncthreads();
  {
    const int e = t>>3, jq = t&7;
    float acc0 = pb2[jq], acc1 = pb2[jq+8];
    const float* qp = B2 + e*ST;
    for(int k=0;k<128;k+=4){
      float4 q4 = *(const float4*)(qp + k);
      acc0 += q4.x*pW2[(k+0)*16+jq]   + q4.y*pW2[(k+1)*16+jq]   + q4.z*pW2[(k+2)*16+jq]   + q4.w*pW2[(k+3)*16+jq];
      acc1 += q4.x*pW2[(k+0)*16+jq+8] + q4.y*pW2[(k+1)*16+jq+8] + q4.z*pW2[(k+2)*16+jq+8] + q4.w*pW2[(k+3)*16+jq+8];
    }
    sEP[e*16+jq]=acc0; sEP[e*16+jq+8]=acc1;
  }
  __syncthreads();
  {
    const int e = t>>3, q = t&7;
    float* pg = pOut + (size_t)sR[e]*128;
    #pragma unroll
    for(int i=0;i<4;i++){
      int f = q + i*8;
      float4 vv = *(const float4*)(Bv + e*ST + f*4);
      float pmv = sEP[e*16 + (f>>1)];
      atomicAdd(pg + f*4 + 0, vv.x*pmv);
      atomicAdd(pg + f*4 + 1, vv.y*pmv);
      atomicAdd(pg + f*4 + 2, vv.z*pmv);
      atomicAdd(pg + f*4 + 3, vv.w*pmv);
    }
  }
}

// ---------------- node kernel (reads pre-aggregated sums; in-place safe on d_out) ----------------
__global__ __launch_bounds__(256) void k_node(
    const float* __restrict__ s, const float* __restrict__ v,
    const float* __restrict__ uW1, const float* __restrict__ ub1,
    const float* __restrict__ uW2, const float* __restrict__ ub2,
    const float* __restrict__ glw, const float* __restrict__ glb,
    const float* __restrict__ grw, const float* __restrict__ grb,
    const float* __restrict__ gow, const float* __restrict__ gob,
    const float* __restrict__ lna,
    const float* __restrict__ mIn, const float* __restrict__ pIn,
    const int* __restrict__ degS,
    float* __restrict__ outS, float* __restrict__ outV)
{
  __shared__ float sX[16*256];
  __shared__ float sT[16*128];
  __shared__ float sP[16*128];
  __shared__ float sG[16*128];
  __shared__ float sNrm[256];
  __shared__ float sInv[16];
  const int t = threadIdx.x;
  const int nb = blockIdx.x*16;
  if(t<16) sInv[t] = rsqrtf((float)degS[nb+t]);
  __syncthreads();
  for(int i=t;i<16*256;i+=256){
    int n=i>>8, c=i&255;
    sX[i] = (c<128) ? s[(size_t)(nb+n)*128 + c]
                    : mIn[(size_t)(nb+n)*128 + (c-128)]*sInv[n];
  }
  for(int i=t;i<16*128;i+=256) sP[i] = pIn[(size_t)nb*128 + i]*sInv[i>>7];
  __syncthreads();
  {
    const int j = t&127, ng = t>>7;
    float acc[8]; const float bb=ub1[j];
    #pragma unroll
    for(int n=0;n<8;n++) acc[n]=bb;
    for(int k=0;k<256;k++){
      float w = uW1[(size_t)k*128+j];
      #pragma unroll
      for(int n=0;n<8;n++) acc[n] += sX[(ng*8+n)*256 + k]*w;
    }
    #pragma unroll
    for(int n=0;n<8;n++) sT[(ng*8+n)*128 + j] = frelu(acc[n]);
  }
  __syncthreads();
  {
    const int j = t&127, ng = t>>7;
    float acc[8]; const float bb=ub2[j];
    #pragma unroll
    for(int n=0;n<8;n++) acc[n]=bb;
    for(int k=0;k<128;k++){
      float w = uW2[(size_t)k*128+j];
      #pragma unroll
      for(int n=0;n<8;n++) acc[n] += sT[(ng*8+n)*128 + k]*w;
    }
    #pragma unroll
    for(int n=0;n<8;n++){
      const size_t r = (size_t)(nb + ng*8 + n)*128 + j;
      outS[r] = s[r] + acc[n];
    }
  }
  float vo[8];
  {
    const int n = t>>4, o = t&15;
    float vl[8], vr[8];
    #pragma unroll
    for(int b=0;b<8;b++){vl[b]=0.f; vr[b]=0.f;}
    vl[0]=glb[o]; vr[0]=grb[o];
    #pragma unroll
    for(int c=0;c<16;c++){
      float4 pa=*(const float4*)(sP + n*128 + c*8);
      float4 pb=*(const float4*)(sP + n*128 + c*8 + 4);
      float4 ga=*(const float4*)(glw + (o*16+c)*4);
      float4 gb=*(const float4*)(grw + (o*16+c)*4);
      vl[0]+=pa.x*ga.x; vl[1]+=pa.y*ga.y; vl[2]+=pa.z*ga.y; vl[3]+=pa.w*ga.y;
      vl[4]+=pb.x*ga.z; vl[5]+=pb.y*ga.z; vl[6]+=pb.z*ga.z; vl[7]+=pb.w*ga.w;
      vr[0]+=pa.x*gb.x; vr[1]+=pa.y*gb.y; vr[2]+=pa.z*gb.y; vr[3]+=pa.w*gb.y;
      vr[4]+=pb.x*gb.z; vr[5]+=pb.y*gb.z; vr[6]+=pb.z*gb.z; vr[7]+=pb.w*gb.w;
    }
    float g[8];
    #pragma unroll
    for(int b=0;b<8;b++) g[b]=0.f;
    const int MASKS[8]={0,1,2,4,3,5,6,7};
    #pragma unroll
    for(int i=0;i<8;i++){
      #pragma unroll
      for(int jj=0;jj<8;jj++){
        const int a=MASKS[i], b=MASKS[jj];
        const int kk=MASKS[a^b];
        int sg=1;
        for(int tt=a>>1; tt; tt>>=1) if(__popc(tt&b)&1) sg=-sg;
        const float pr = vl[i]*vr[jj];
        g[kk] += (sg>0)? pr : -pr;
      }
    }
    *(float4*)(sG + n*128 + o*8)     = make_float4(g[0],g[1],g[2],g[3]);
    *(float4*)(sG + n*128 + o*8 + 4) = make_float4(g[4],g[5],g[6],g[7]);
  }
  __syncthreads();
  {
    const int n = t>>4, o = t&15;
    #pragma unroll
    for(int b=0;b<8;b++) vo[b]=0.f;
    vo[0]=gob[o];
    #pragma unroll
    for(int c=0;c<32;c++){
      const float* src = (c<16) ? (sG + n*128 + c*8) : (sP + n*128 + (c-16)*8);
      float4 sa=*(const float4*)(src);
      float4 sb=*(const float4*)(src+4);
      float4 gw=*(const float4*)(gow + (o*32+c)*4);
      vo[0]+=sa.x*gw.x; vo[1]+=sa.y*gw.y; vo[2]+=sa.z*gw.y; vo[3]+=sa.w*gw.y;
      vo[4]+=sb.x*gw.z; vo[5]+=sb.y*gw.z; vo[6]+=sb.z*gw.z; vo[7]+=sb.w*gw.w;
    }
    float ssum=0.f;
    #pragma unroll
    for(int b=0;b<8;b++) ssum+=vo[b]*vo[b];
    sNrm[t]=sqrtf(ssum);
  }
  __syncthreads();
  {
    const int n = t>>4, o = t&15;
    float mn=0.f;
    #pragma unroll
    for(int c=0;c<16;c++) mn += sNrm[n*16+c];
    mn = mn*(1.f/16.f) + 1e-6f;
    const float sc = lna[o]/mn;
    const size_t base = (size_t)(nb+n)*128 + o*8;
    float4 v0=*(const float4*)(v+base);
    float4 v1=*(const float4*)(v+base+4);
    *(float4*)(outV+base)   = make_float4(vo[0]*sc+v0.x, vo[1]*sc+v0.y, vo[2]*sc+v0.z, vo[3]*sc+v0.w);
    *(float4*)(outV+base+4) = make_float4(vo[4]*sc+v1.x, vo[5]*sc+v1.y, vo[6]*sc+v1.z, vo[7]*sc+v1.w);
  }
}

extern "C" void kernel_launch(void* const* d_in, const int* in_sizes, int n_in,
                              void* d_out, int out_size, void* d_ws, size_t ws_size,
                              hipStream_t stream){
  (void)in_sizes; (void)n_in; (void)out_size;
  const float* s    = (const float*)d_in[0];
  const float* v    = (const float*)d_in[1];
  const int*   eidx = (const int*)d_in[2];
  const float* Wvw  = (const float*)d_in[3];
  const float* Wvb  = (const float*)d_in[4];
  const float* mnW1 = (const float*)d_in[5];
  const float* mnb1 = (const float*)d_in[6];
  const float* mnW2 = (const float*)d_in[7];
  const float* mnb2 = (const float*)d_in[8];
  const float* pnW1 = (const float*)d_in[9];
  const float* pnb1 = (const float*)d_in[10];
  const float* pnW2 = (const float*)d_in[11];
  const float* pnb2 = (const float*)d_in[12];
  const float* unW1 = (const float*)d_in[13];
  const float* unb1 = (const float*)d_in[14];
  const float* unW2 = (const float*)d_in[15];
  const float* unb2 = (const float*)d_in[16];
  const float* glw  = (const float*)d_in[17];
  const float* glb  = (const float*)d_in[18];
  const float* grw  = (const float*)d_in[19];
  const float* grb  = (const float*)d_in[20];
  const float* gow  = (const float*)d_in[21];
  const float* gob  = (const float*)d_in[22];
  const float* lna  = (const float*)d_in[23];

  float* outS = (float*)d_out;
  float* outV = outS + (size_t)NN*128;

  // CSR path workspace: A,Bn (20.48 MB) + degS,cntR,off,cur,eord (1.6 MB)
  const size_t need = ((size_t)2*NN*128)*sizeof(float)
                    + ((size_t)3*NN + 1 + NN + NE)*sizeof(int);

  if(ws_size >= need){
    float* A    = (float*)d_ws;
    float* Bn   = A + (size_t)NN*128;
    int* degS = (int*)(Bn + (size_t)NN*128);
    int* cntR = degS + NN;
    int* off  = cntR + NN;       // NN+1
    int* cur  = off + NN + 1;
    int* eord = cur + NN;
    float* Magg = outS;          // d_out staging, consumed in-place by k_node
    float* Pagg = outV;

    hipMemsetAsync(degS, 0, (size_t)2*NN*sizeof(int), stream);
    k_hist<<<(NE+255)/256, 256, 0, stream>>>(eidx, degS, cntR, 1);
    k_scan<<<1, 256, 0, stream>>>(cntR, off, cur);
    k_fill<<<(NE+255)/256, 256, 0, stream>>>(eidx, cur, eord);
    k_ab<<<NN/8, 256, 0, stream>>>(s, mnW1, A, Bn);
    k_edge2<<<NN/GN, 256, 0, stream>>>(v, eidx, Wvw, Wvb, mnW1 + 256*128, mnb1,
                                       mnW2, mnb2, pnW1, pnb1, pnW2, pnb2,
                                       A, Bn, off, eord, Magg, Pagg);
    k_node<<<NN/16, 256, 0, stream>>>(s, v, unW1, unb1, unW2, unb2,
                                      glw, glb, grw, grb, gow, gob, lna,
                                      Magg, Pagg, degS, outS, outV);
  } else {
    // fallback: atomic aggregation (proven R0 path)
    float* A    = outS;
    float* Bn   = outV;
    float* ws   = (float*)d_ws;
    float* Magg = ws;
    float* Pagg = ws + (size_t)NN*128;
    int*   degS = (int*)(ws + (size_t)2*NN*128);
    hipMemsetAsync(Magg, 0, (size_t)2*NN*128*sizeof(float) + (size_t)NN*sizeof(int), stream);
    k_hist<<<(NE+255)/256, 256, 0, stream>>>(eidx, degS, (int*)0, 0);
    k_ab<<<NN/8, 256, 0, stream>>>(s, mnW1, A, Bn);
    k_edge0<<<NE/ET, 256, 0, stream>>>(v, eidx, Wvw, Wvb, mnW1 + 256*128, mnb1,
                                       mnW2, mnb2, pnW1, pnb1, pnW2, pnb2,
                                       A, Bn, Magg, Pagg);
    k_node<<<NN/16, 256, 0, stream>>>(s, v, unW1, unb1, unW2, unb2,
                                      glw, glb, grw, grb, gow, gob, lna,
                                      Magg, Pagg, degS, outS, outV);
  }
}

// Round 5
// 995.800 us; speedup vs baseline: 4.2603x; 4.2603x over previous
//
#include <hip/hip_runtime.h>
#include <math.h>

#define NN 20000
#define NE 320000
#define ET 32          // edges per tile
#define ST 132         // LDS row stride in floats

__device__ __forceinline__ float frelu(float x){ return fmaxf(x, 0.f); }

// ---------------- histograms: degS over send (normalization), cntR over rec (sort) ----------------
__global__ void k_hist(const int* __restrict__ eidx, int* __restrict__ degS,
                       int* __restrict__ cntR, int mode){
  int t = blockIdx.x*256 + threadIdx.x;
  if(t < NE){
    atomicAdd(&degS[eidx[t]], 1);
    if(mode) atomicAdd(&cntR[eidx[NE+t]], 1);
  }
}

// ---------------- exclusive scan of cntR -> cur[N] (single block) ----------------
__global__ __launch_bounds__(256) void k_scan(const int* __restrict__ cntR,
                                              int* __restrict__ cur){
  __shared__ int part[256];
  __shared__ int pre[256];
  const int t = threadIdx.x;
  const int start = t*80, end = min(start+80, NN);
  int sm = 0;
  for(int n=start;n<end;n++) sm += cntR[n];
  part[t] = sm;
  __syncthreads();
  if(t==0){ int r=0; for(int i=0;i<256;i++){ pre[i]=r; r+=part[i]; } }
  __syncthreads();
  int run = pre[t];
  for(int n=start;n<end;n++){ cur[n]=run; run += cntR[n]; }
}

// ---------------- scatter edge ids into rec-sorted order ----------------
__global__ void k_fill(const int* __restrict__ eidx, int* __restrict__ cur,
                       int* __restrict__ eord){
  int e = blockIdx.x*256 + threadIdx.x;
  if(e < NE){
    int r = eidx[NE+e];
    int p = atomicAdd(&cur[r], 1);
    eord[p] = e;
  }
}

// ---------------- per-node precompute: A = s@W1[0:128], B = s@W1[128:256] ----------------
__global__ __launch_bounds__(256) void k_ab(const float* __restrict__ s,
                                            const float* __restrict__ W1,
                                            float* __restrict__ A,
                                            float* __restrict__ B){
  __shared__ float sx[8*128];
  const int nb = blockIdx.x*8;
  for(int i=threadIdx.x; i<8*128; i+=256) sx[i] = s[(size_t)nb*128 + i];
  __syncthreads();
  const int col = threadIdx.x;
  const int j = col & 127;
  const float* w = W1 + (col < 128 ? 0 : 128*128) + j;
  float acc[8];
  #pragma unroll
  for(int n=0;n<8;n++) acc[n]=0.f;
  for(int k=0;k<128;k++){
    float wv = w[(size_t)k*128];
    #pragma unroll
    for(int n=0;n<8;n++) acc[n] += sx[n*128+k]*wv;
  }
  float* dst = (col<128 ? A : B) + (size_t)nb*128 + j;
  #pragma unroll
  for(int n=0;n<8;n++) dst[(size_t)n*128] = acc[n];
}

// ======================= flat edge kernel, rec-sorted + segmented atomics =======================
// SORTED=1: edges come via eord (rec-sorted); Ph8 does per-column segment reduce, ~3 atomic
// rows per block instead of 32. SORTED=0: original per-edge atomic scatter (fallback).
template<int SORTED>
__global__ __launch_bounds__(256) void k_edge(
    const float* __restrict__ v, const int* __restrict__ eidx,
    const float* __restrict__ Wvw, const float* __restrict__ Wvb,
    const float* __restrict__ W1c, const float* __restrict__ b1,
    const float* __restrict__ W2,  const float* __restrict__ b2,
    const float* __restrict__ pW1, const float* __restrict__ pb1,
    const float* __restrict__ pW2, const float* __restrict__ pb2,
    const float* __restrict__ A,   const float* __restrict__ Bn,
    const int* __restrict__ eord,
    float* __restrict__ Magg, float* __restrict__ Pagg)
{
  __shared__ float B0[ET*ST];   // d -> m
  __shared__ float Bv[ET*ST];   // v_ij
  __shared__ float B2[ET*ST];   // h -> q -> pos_m
  __shared__ float sEP[ET*16];  // edge_attr, then pm
  __shared__ int sS[ET], sR[ET];
  const int t  = threadIdx.x;
  const int e0 = blockIdx.x * ET;

  if(t<ET){
    int e = SORTED ? eord[e0+t] : (e0+t);
    sS[t]=eidx[e]; sR[t]=eidx[NE+e];
  }
  __syncthreads();

  // Ph1: d = v[rec] - v[send]
  {
    const int e = t>>3, q = t&7;
    const float4* vs = (const float4*)(v + (size_t)sS[e]*128);
    const float4* vr = (const float4*)(v + (size_t)sR[e]*128);
    #pragma unroll
    for(int i=0;i<4;i++){
      int f = q + i*8;
      float4 a = vr[f], b = vs[f];
      *(float4*)(B0 + e*ST + f*4) = make_float4(a.x-b.x, a.y-b.y, a.z-b.z, a.w-b.w);
    }
  }
  __syncthreads();

  // Ph2: v_ij = mv_linear(d, Wv) ; edge_attr = sum_b v_ij^2
  {
    const int e = t>>3, q = t&7;
    float a0[8], a1[8];
    #pragma unroll
    for(int b=0;b<8;b++){a0[b]=0.f;a1[b]=0.f;}
    a0[0]=Wvb[q]; a1[0]=Wvb[q+8];
    const float* dp = B0 + e*ST;
    #pragma unroll
    for(int c=0;c<16;c++){
      float4 da=*(const float4*)(dp + c*8);
      float4 db=*(const float4*)(dp + c*8 + 4);
      float4 g0=*(const float4*)(Wvw + (q*16+c)*4);
      float4 g1=*(const float4*)(Wvw + ((q+8)*16+c)*4);
      a0[0]+=da.x*g0.x; a0[1]+=da.y*g0.y; a0[2]+=da.z*g0.y; a0[3]+=da.w*g0.y;
      a0[4]+=db.x*g0.z; a0[5]+=db.y*g0.z; a0[6]+=db.z*g0.z; a0[7]+=db.w*g0.w;
      a1[0]+=da.x*g1.x; a1[1]+=da.y*g1.y; a1[2]+=da.z*g1.y; a1[3]+=da.w*g1.y;
      a1[4]+=db.x*g1.z; a1[5]+=db.y*g1.z; a1[6]+=db.z*g1.z; a1[7]+=db.w*g1.w;
    }
    *(float4*)(Bv + e*ST + q*8)       = make_float4(a0[0],a0[1],a0[2],a0[3]);
    *(float4*)(Bv + e*ST + q*8 + 4)   = make_float4(a0[4],a0[5],a0[6],a0[7]);
    *(float4*)(Bv + e*ST + (q+8)*8)   = make_float4(a1[0],a1[1],a1[2],a1[3]);
    *(float4*)(Bv + e*ST + (q+8)*8+4) = make_float4(a1[4],a1[5],a1[6],a1[7]);
    float e0s=0.f, e1s=0.f;
    #pragma unroll
    for(int b=0;b<8;b++){ e0s+=a0[b]*a0[b]; e1s+=a1[b]*a1[b]; }
    sEP[e*16+q]=e0s; sEP[e*16+q+8]=e1s;
  }
  __syncthreads();

  // Ph3: h = relu(A[send] + B[rec] + ea@W1c + b1)
  {
    const int j = t&127, eg = t>>7;
    float w1c[16];
    #pragma unroll
    for(int c=0;c<16;c++) w1c[c]=W1c[(size_t)c*128 + j];
    const float bb = b1[j];
    for(int ei=0; ei<16; ei++){
      const int e = eg*16 + ei;
      float acc = A[(size_t)sS[e]*128 + j] + Bn[(size_t)sR[e]*128 + j] + bb;
      #pragma unroll
      for(int c=0;c<16;c++) acc += sEP[e*16+c]*w1c[c];
      B2[e*ST + j] = frelu(acc);
    }
  }
  __syncthreads();

  // Ph4: m = h@W2 + b2 -> B0 (SORTED=0: also atomic scatter here)
  {
    const int jq = t&31, eg = t>>5;
    const int j0 = jq*4;
    float4 bb = *(const float4*)(b2 + j0);
    float acc[4][4];
    #pragma unroll
    for(int a=0;a<4;a++){ acc[a][0]=bb.x; acc[a][1]=bb.y; acc[a][2]=bb.z; acc[a][3]=bb.w; }
    for(int k=0;k<128;k+=4){
      float4 w0=*(const float4*)(W2 + (size_t)(k+0)*128 + j0);
      float4 w1=*(const float4*)(W2 + (size_t)(k+1)*128 + j0);
      float4 w2=*(const float4*)(W2 + (size_t)(k+2)*128 + j0);
      float4 w3=*(const float4*)(W2 + (size_t)(k+3)*128 + j0);
      #pragma unroll
      for(int a=0;a<4;a++){
        float4 h4=*(const float4*)(B2 + (eg*4+a)*ST + k);
        acc[a][0] += h4.x*w0.x + h4.y*w1.x + h4.z*w2.x + h4.w*w3.x;
        acc[a][1] += h4.x*w0.y + h4.y*w1.y + h4.z*w2.y + h4.w*w3.y;
        acc[a][2] += h4.x*w0.z + h4.y*w1.z + h4.z*w2.z + h4.w*w3.z;
        acc[a][3] += h4.x*w0.w + h4.y*w1.w + h4.z*w2.w + h4.w*w3.w;
      }
    }
    #pragma unroll
    for(int a=0;a<4;a++){
      const int e = eg*4+a;
      *(float4*)(B0 + e*ST + j0) = make_float4(acc[a][0],acc[a][1],acc[a][2],acc[a][3]);
      if(!SORTED){
        float* mg = Magg + (size_t)sR[e]*128 + j0;
        atomicAdd(mg+0, acc[a][0]); atomicAdd(mg+1, acc[a][1]);
        atomicAdd(mg+2, acc[a][2]); atomicAdd(mg+3, acc[a][3]);
      }
    }
  }
  __syncthreads();

  // Ph5: q = relu(m@pW1 + pb1) -> B2
  {
    const int jq = t&31, eg = t>>5;
    const int j0 = jq*4;
    float4 bb = *(const float4*)(pb1 + j0);
    float acc[4][4];
    #pragma unroll
    for(int a=0;a<4;a++){ acc[a][0]=bb.x; acc[a][1]=bb.y; acc[a][2]=bb.z; acc[a][3]=bb.w; }
    for(int k=0;k<128;k+=4){
      float4 w0=*(const float4*)(pW1 + (size_t)(k+0)*128 + j0);
      float4 w1=*(const float4*)(pW1 + (size_t)(k+1)*128 + j0);
      float4 w2=*(const float4*)(pW1 + (size_t)(k+2)*128 + j0);
      float4 w3=*(const float4*)(pW1 + (size_t)(k+3)*128 + j0);
      #pragma unroll
      for(int a=0;a<4;a++){
        float4 m4=*(const float4*)(B0 + (eg*4+a)*ST + k);
        acc[a][0] += m4.x*w0.x + m4.y*w1.x + m4.z*w2.x + m4.w*w3.x;
        acc[a][1] += m4.x*w0.y + m4.y*w1.y + m4.z*w2.y + m4.w*w3.y;
        acc[a][2] += m4.x*w0.z + m4.y*w1.z + m4.z*w2.z + m4.w*w3.z;
        acc[a][3] += m4.x*w0.w + m4.y*w1.w + m4.z*w2.w + m4.w*w3.w;
      }
    }
    #pragma unroll
    for(int a=0;a<4;a++){
      const int e = eg*4+a;
      *(float4*)(B2 + e*ST + j0) = make_float4(frelu(acc[a][0]),frelu(acc[a][1]),frelu(acc[a][2]),frelu(acc[a][3]));
    }
  }
  __syncthreads();

  // Ph6: pm = q@pW2 + pb2 -> sEP
  {
    const int e = t>>3, jq = t&7;
    float acc0 = pb2[jq], acc1 = pb2[jq+8];
    const float* qp = B2 + e*ST;
    for(int k=0;k<128;k+=4){
      float4 q4 = *(const float4*)(qp + k);
      acc0 += q4.x*pW2[(k+0)*16+jq]   + q4.y*pW2[(k+1)*16+jq]   + q4.z*pW2[(k+2)*16+jq]   + q4.w*pW2[(k+3)*16+jq];
      acc1 += q4.x*pW2[(k+0)*16+jq+8] + q4.y*pW2[(k+1)*16+jq+8] + q4.z*pW2[(k+2)*16+jq+8] + q4.w*pW2[(k+3)*16+jq+8];
    }
    sEP[e*16+jq]=acc0; sEP[e*16+jq+8]=acc1;
  }
  __syncthreads();

  // Ph7: pos_m = v_ij * pm -> B2 (SORTED=0: atomic scatter instead)
  {
    const int e = t>>3, q = t&7;
    #pragma unroll
    for(int i=0;i<4;i++){
      int f = q + i*8;
      float4 vv = *(const float4*)(Bv + e*ST + f*4);
      float pmv = sEP[e*16 + (f>>1)];
      if(SORTED){
        *(float4*)(B2 + e*ST + f*4) = make_float4(vv.x*pmv, vv.y*pmv, vv.z*pmv, vv.w*pmv);
      } else {
        float* pg = Pagg + (size_t)sR[e]*128;
        atomicAdd(pg + f*4 + 0, vv.x*pmv);
        atomicAdd(pg + f*4 + 1, vv.y*pmv);
        atomicAdd(pg + f*4 + 2, vv.z*pmv);
        atomicAdd(pg + f*4 + 3, vv.w*pmv);
      }
    }
  }

  // Ph8 (SORTED only): rec-segmented reduce -> one atomicAdd per (segment, column).
  // Edges are rec-sorted, so a block spans ~2-3 segments; branch is wave-uniform (sR broadcast).
  if(SORTED){
    __syncthreads();
    const float* src = (t<128) ? B0 : B2;
    float* dst = (t<128) ? Magg : Pagg;
    const int j = t&127;
    float run = 0.f;
    int cr = sR[0];
    #pragma unroll 4
    for(int e=0;e<ET;e++){
      const int r = sR[e];
      if(r!=cr){
        atomicAdd(&dst[(size_t)cr*128 + j], run);
        run = 0.f; cr = r;
      }
      run += src[e*ST + j];
    }
    atomicAdd(&dst[(size_t)cr*128 + j], run);
  }
}

// ---------------- node kernel (reads pre-aggregated sums) ----------------
__global__ __launch_bounds__(256) void k_node(
    const float* __restrict__ s, const float* __restrict__ v,
    const float* __restrict__ uW1, const float* __restrict__ ub1,
    const float* __restrict__ uW2, const float* __restrict__ ub2,
    const float* __restrict__ glw, const float* __restrict__ glb,
    const float* __restrict__ grw, const float* __restrict__ grb,
    const float* __restrict__ gow, const float* __restrict__ gob,
    const float* __restrict__ lna,
    const float* __restrict__ mIn, const float* __restrict__ pIn,
    const int* __restrict__ degS,
    float* __restrict__ outS, float* __restrict__ outV)
{
  __shared__ float sX[16*256];
  __shared__ float sT[16*128];
  __shared__ float sP[16*128];
  __shared__ float sG[16*128];
  __shared__ float sNrm[256];
  __shared__ float sInv[16];
  const int t = threadIdx.x;
  const int nb = blockIdx.x*16;
  if(t<16) sInv[t] = rsqrtf((float)degS[nb+t]);
  __syncthreads();
  for(int i=t;i<16*256;i+=256){
    int n=i>>8, c=i&255;
    sX[i] = (c<128) ? s[(size_t)(nb+n)*128 + c]
                    : mIn[(size_t)(nb+n)*128 + (c-128)]*sInv[n];
  }
  for(int i=t;i<16*128;i+=256) sP[i] = pIn[(size_t)nb*128 + i]*sInv[i>>7];
  __syncthreads();
  {
    const int j = t&127, ng = t>>7;
    float acc[8]; const float bb=ub1[j];
    #pragma unroll
    for(int n=0;n<8;n++) acc[n]=bb;
    for(int k=0;k<256;k++){
      float w = uW1[(size_t)k*128+j];
      #pragma unroll
      for(int n=0;n<8;n++) acc[n] += sX[(ng*8+n)*256 + k]*w;
    }
    #pragma unroll
    for(int n=0;n<8;n++) sT[(ng*8+n)*128 + j] = frelu(acc[n]);
  }
  __syncthreads();
  {
    const int j = t&127, ng = t>>7;
    float acc[8]; const float bb=ub2[j];
    #pragma unroll
    for(int n=0;n<8;n++) acc[n]=bb;
    for(int k=0;k<128;k++){
      float w = uW2[(size_t)k*128+j];
      #pragma unroll
      for(int n=0;n<8;n++) acc[n] += sT[(ng*8+n)*128 + k]*w;
    }
    #pragma unroll
    for(int n=0;n<8;n++){
      const size_t r = (size_t)(nb + ng*8 + n)*128 + j;
      outS[r] = s[r] + acc[n];
    }
  }
  float vo[8];
  {
    const int n = t>>4, o = t&15;
    float vl[8], vr[8];
    #pragma unroll
    for(int b=0;b<8;b++){vl[b]=0.f; vr[b]=0.f;}
    vl[0]=glb[o]; vr[0]=grb[o];
    #pragma unroll
    for(int c=0;c<16;c++){
      float4 pa=*(const float4*)(sP + n*128 + c*8);
      float4 pb=*(const float4*)(sP + n*128 + c*8 + 4);
      float4 ga=*(const float4*)(glw + (o*16+c)*4);
      float4 gb=*(const float4*)(grw + (o*16+c)*4);
      vl[0]+=pa.x*ga.x; vl[1]+=pa.y*ga.y; vl[2]+=pa.z*ga.y; vl[3]+=pa.w*ga.y;
      vl[4]+=pb.x*ga.z; vl[5]+=pb.y*ga.z; vl[6]+=pb.z*ga.z; vl[7]+=pb.w*ga.w;
      vr[0]+=pa.x*gb.x; vr[1]+=pa.y*gb.y; vr[2]+=pa.z*gb.y; vr[3]+=pa.w*gb.y;
      vr[4]+=pb.x*gb.z; vr[5]+=pb.y*gb.z; vr[6]+=pb.z*gb.z; vr[7]+=pb.w*gb.w;
    }
    float g[8];
    #pragma unroll
    for(int b=0;b<8;b++) g[b]=0.f;
    const int MASKS[8]={0,1,2,4,3,5,6,7};
    #pragma unroll
    for(int i=0;i<8;i++){
      #pragma unroll
      for(int jj=0;jj<8;jj++){
        const int a=MASKS[i], b=MASKS[jj];
        const int kk=MASKS[a^b];
        int sg=1;
        for(int tt=a>>1; tt; tt>>=1) if(__popc(tt&b)&1) sg=-sg;
        const float pr = vl[i]*vr[jj];
        g[kk] += (sg>0)? pr : -pr;
      }
    }
    *(float4*)(sG + n*128 + o*8)     = make_float4(g[0],g[1],g[2],g[3]);
    *(float4*)(sG + n*128 + o*8 + 4) = make_float4(g[4],g[5],g[6],g[7]);
  }
  __syncthreads();
  {
    const int n = t>>4, o = t&15;
    #pragma unroll
    for(int b=0;b<8;b++) vo[b]=0.f;
    vo[0]=gob[o];
    #pragma unroll
    for(int c=0;c<32;c++){
      const float* src = (c<16) ? (sG + n*128 + c*8) : (sP + n*128 + (c-16)*8);
      float4 sa=*(const float4*)(src);
      float4 sb=*(const float4*)(src+4);
      float4 gw=*(const float4*)(gow + (o*32+c)*4);
      vo[0]+=sa.x*gw.x; vo[1]+=sa.y*gw.y; vo[2]+=sa.z*gw.y; vo[3]+=sa.w*gw.y;
      vo[4]+=sb.x*gw.z; vo[5]+=sb.y*gw.z; vo[6]+=sb.z*gw.z; vo[7]+=sb.w*gw.w;
    }
    float ssum=0.f;
    #pragma unroll
    for(int b=0;b<8;b++) ssum+=vo[b]*vo[b];
    sNrm[t]=sqrtf(ssum);
  }
  __syncthreads();
  {
    const int n = t>>4, o = t&15;
    float mn=0.f;
    #pragma unroll
    for(int c=0;c<16;c++) mn += sNrm[n*16+c];
    mn = mn*(1.f/16.f) + 1e-6f;
    const float sc = lna[o]/mn;
    const size_t base = (size_t)(nb+n)*128 + o*8;
    float4 v0=*(const float4*)(v+base);
    float4 v1=*(const float4*)(v+base+4);
    *(float4*)(outV+base)   = make_float4(vo[0]*sc+v0.x, vo[1]*sc+v0.y, vo[2]*sc+v0.z, vo[3]*sc+v0.w);
    *(float4*)(outV+base+4) = make_float4(vo[4]*sc+v1.x, vo[5]*sc+v1.y, vo[6]*sc+v1.z, vo[7]*sc+v1.w);
  }
}

extern "C" void kernel_launch(void* const* d_in, const int* in_sizes, int n_in,
                              void* d_out, int out_size, void* d_ws, size_t ws_size,
                              hipStream_t stream){
  (void)in_sizes; (void)n_in; (void)out_size;
  const float* s    = (const float*)d_in[0];
  const float* v    = (const float*)d_in[1];
  const int*   eidx = (const int*)d_in[2];
  const float* Wvw  = (const float*)d_in[3];
  const float* Wvb  = (const float*)d_in[4];
  const float* mnW1 = (const float*)d_in[5];
  const float* mnb1 = (const float*)d_in[6];
  const float* mnW2 = (const float*)d_in[7];
  const float* mnb2 = (const float*)d_in[8];
  const float* pnW1 = (const float*)d_in[9];
  const float* pnb1 = (const float*)d_in[10];
  const float* pnW2 = (const float*)d_in[11];
  const float* pnb2 = (const float*)d_in[12];
  const float* unW1 = (const float*)d_in[13];
  const float* unb1 = (const float*)d_in[14];
  const float* unW2 = (const float*)d_in[15];
  const float* unb2 = (const float*)d_in[16];
  const float* glw  = (const float*)d_in[17];
  const float* glb  = (const float*)d_in[18];
  const float* grw  = (const float*)d_in[19];
  const float* grb  = (const float*)d_in[20];
  const float* gow  = (const float*)d_in[21];
  const float* gob  = (const float*)d_in[22];
  const float* lna  = (const float*)d_in[23];

  float* outS = (float*)d_out;
  float* outV = outS + (size_t)NN*128;
  float* A    = outS;            // A/Bn stage in d_out (dead until k_node writes) — proven R0 pattern
  float* Bn   = outV;

  // ws: Magg, Pagg (20.48 MB) + degS, cntR, cur, eord (1.52 MB) = 22.0 MB (proven budget in R2/R3)
  const size_t need = ((size_t)2*NN*128)*sizeof(float) + ((size_t)3*NN + NE)*sizeof(int);

  float* Magg = (float*)d_ws;
  float* Pagg = Magg + (size_t)NN*128;
  int* degS = (int*)(Pagg + (size_t)NN*128);
  int* cntR = degS + NN;
  int* cur  = cntR + NN;
  int* eord = cur + NN;

  if(ws_size >= need){
    // zero Magg, Pagg, degS, cntR (contiguous)
    hipMemsetAsync(Magg, 0, (size_t)2*NN*128*sizeof(float) + (size_t)2*NN*sizeof(int), stream);
    k_hist<<<(NE+255)/256, 256, 0, stream>>>(eidx, degS, cntR, 1);
    k_scan<<<1, 256, 0, stream>>>(cntR, cur);
    k_fill<<<(NE+255)/256, 256, 0, stream>>>(eidx, cur, eord);
    k_ab<<<NN/8, 256, 0, stream>>>(s, mnW1, A, Bn);
    k_edge<1><<<NE/ET, 256, 0, stream>>>(v, eidx, Wvw, Wvb, mnW1 + 256*128, mnb1,
                                         mnW2, mnb2, pnW1, pnb1, pnW2, pnb2,
                                         A, Bn, eord, Magg, Pagg);
    k_node<<<NN/16, 256, 0, stream>>>(s, v, unW1, unb1, unW2, unb2,
                                      glw, glb, grw, grb, gow, gob, lna,
                                      Magg, Pagg, degS, outS, outV);
  } else {
    // fallback: atomic aggregation (proven R0 path)
    hipMemsetAsync(Magg, 0, (size_t)2*NN*128*sizeof(float) + (size_t)NN*sizeof(int), stream);
    k_hist<<<(NE+255)/256, 256, 0, stream>>>(eidx, degS, (int*)0, 0);
    k_ab<<<NN/8, 256, 0, stream>>>(s, mnW1, A, Bn);
    k_edge<0><<<NE/ET, 256, 0, stream>>>(v, eidx, Wvw, Wvb, mnW1 + 256*128, mnb1,
                                         mnW2, mnb2, pnW1, pnb1, pnW2, pnb2,
                                         A, Bn, (int*)0, Magg, Pagg);
    k_node<<<NN/16, 256, 0, stream>>>(s, v, unW1, unb1, unW2, unb2,
                                      glw, glb, grw, grb, gow, gob, lna,
                                      Magg, Pagg, degS, outS, outV);
  }
}

// Round 7
// 893.932 us; speedup vs baseline: 4.7458x; 1.1140x over previous
//
#include <hip/hip_runtime.h>
#include <math.h>

#define NN 20000
#define NE 320000
#define ET 32          // edges per tile
#define ST 132         // LDS row stride in floats

typedef float v2f __attribute__((ext_vector_type(2)));
__device__ __forceinline__ v2f fma2(v2f a, v2f b, v2f c){ return __builtin_elementwise_fma(a,b,c); }
__device__ __forceinline__ v2f mk2(float x, float y){ v2f r; r.x=x; r.y=y; return r; }

__device__ __forceinline__ float frelu(float x){ return fmaxf(x, 0.f); }

// ---------------- histograms: degS over send (normalization), cntR over rec (sort) ----------------
__global__ void k_hist(const int* __restrict__ eidx, int* __restrict__ degS,
                       int* __restrict__ cntR, int mode){
  int t = blockIdx.x*256 + threadIdx.x;
  if(t < NE){
    atomicAdd(&degS[eidx[t]], 1);
    if(mode) atomicAdd(&cntR[eidx[NE+t]], 1);
  }
}

// ---------------- exclusive scan of cntR -> cur[N] (single block) ----------------
__global__ __launch_bounds__(256) void k_scan(const int* __restrict__ cntR,
                                              int* __restrict__ cur){
  __shared__ int part[256];
  __shared__ int pre[256];
  const int t = threadIdx.x;
  const int start = t*80, end = min(start+80, NN);
  int sm = 0;
  for(int n=start;n<end;n++) sm += cntR[n];
  part[t] = sm;
  __syncthreads();
  if(t==0){ int r=0; for(int i=0;i<256;i++){ pre[i]=r; r+=part[i]; } }
  __syncthreads();
  int run = pre[t];
  for(int n=start;n<end;n++){ cur[n]=run; run += cntR[n]; }
}

// ---------------- scatter edge ids into rec-sorted order ----------------
__global__ void k_fill(const int* __restrict__ eidx, int* __restrict__ cur,
                       int* __restrict__ eord){
  int e = blockIdx.x*256 + threadIdx.x;
  if(e < NE){
    int r = eidx[NE+e];
    int p = atomicAdd(&cur[r], 1);
    eord[p] = e;
  }
}

// ---------------- per-node precompute: A = s@W1[0:128], B = s@W1[128:256] ----------------
__global__ __launch_bounds__(256) void k_ab(const float* __restrict__ s,
                                            const float* __restrict__ W1,
                                            float* __restrict__ A,
                                            float* __restrict__ B){
  __shared__ float sx[8*128];
  const int nb = blockIdx.x*8;
  for(int i=threadIdx.x; i<8*128; i+=256) sx[i] = s[(size_t)nb*128 + i];
  __syncthreads();
  const int col = threadIdx.x;
  const int j = col & 127;
  const float* w = W1 + (col < 128 ? 0 : 128*128) + j;
  v2f acc[4];
  #pragma unroll
  for(int n=0;n<4;n++) acc[n]=mk2(0.f,0.f);
  for(int k=0;k<128;k++){
    float wv = w[(size_t)k*128];
    v2f wv2 = mk2(wv, wv);
    #pragma unroll
    for(int n=0;n<4;n++){
      v2f x = mk2(sx[(2*n)*128+k], sx[(2*n+1)*128+k]);
      acc[n] = fma2(x, wv2, acc[n]);
    }
  }
  float* dst = (col<128 ? A : B) + (size_t)nb*128 + j;
  #pragma unroll
  for(int n=0;n<4;n++){
    dst[(size_t)(2*n)*128]   = acc[n].x;
    dst[(size_t)(2*n+1)*128] = acc[n].y;
  }
}

// ======================= flat edge kernel, rec-sorted + segmented atomics =======================
// SORTED=1: edges via eord (rec-sorted); Ph8 per-column segment reduce (~3 atomic rows/block).
// SORTED=0: per-edge atomic scatter (fallback). Inner GEMM phases use float2 packed fp32.
template<int SORTED>
__global__ __launch_bounds__(256) void k_edge(
    const float* __restrict__ v, const int* __restrict__ eidx,
    const float* __restrict__ Wvw, const float* __restrict__ Wvb,
    const float* __restrict__ W1c, const float* __restrict__ b1,
    const float* __restrict__ W2,  const float* __restrict__ b2,
    const float* __restrict__ pW1, const float* __restrict__ pb1,
    const float* __restrict__ pW2, const float* __restrict__ pb2,
    const float* __restrict__ A,   const float* __restrict__ Bn,
    const int* __restrict__ eord,
    float* __restrict__ Magg, float* __restrict__ Pagg)
{
  __shared__ float B0[ET*ST];   // d -> m
  __shared__ float Bv[ET*ST];   // v_ij
  __shared__ float B2[ET*ST];   // h -> q -> pos_m
  __shared__ float sEP[ET*16];  // edge_attr, then pm
  __shared__ int sS[ET], sR[ET];
  const int t  = threadIdx.x;
  const int e0 = blockIdx.x * ET;

  if(t<ET){
    int e = SORTED ? eord[e0+t] : (e0+t);
    sS[t]=eidx[e]; sR[t]=eidx[NE+e];
  }
  __syncthreads();

  // Ph1: d = v[rec] - v[send]
  {
    const int e = t>>3, q = t&7;
    const float4* vs = (const float4*)(v + (size_t)sS[e]*128);
    const float4* vr = (const float4*)(v + (size_t)sR[e]*128);
    #pragma unroll
    for(int i=0;i<4;i++){
      int f = q + i*8;
      float4 a = vr[f], b = vs[f];
      *(float4*)(B0 + e*ST + f*4) = make_float4(a.x-b.x, a.y-b.y, a.z-b.z, a.w-b.w);
    }
  }
  __syncthreads();

  // Ph2: v_ij = mv_linear(d, Wv) ; edge_attr = sum_b v_ij^2   (packed fp32, blade pairs)
  {
    const int e = t>>3, q = t&7;
    v2f a0[4], a1[4];            // blade pairs (0,1)(2,3)(4,5)(6,7)
    #pragma unroll
    for(int b=0;b<4;b++){ a0[b]=mk2(0.f,0.f); a1[b]=mk2(0.f,0.f); }
    a0[0].x=Wvb[q]; a1[0].x=Wvb[q+8];
    const float* dp = B0 + e*ST;
    #pragma unroll
    for(int c=0;c<16;c++){
      float4 da=*(const float4*)(dp + c*8);
      float4 db=*(const float4*)(dp + c*8 + 4);
      float4 g0=*(const float4*)(Wvw + (q*16+c)*4);
      float4 g1=*(const float4*)(Wvw + ((q+8)*16+c)*4);
      a0[0]=fma2(mk2(da.x,da.y), mk2(g0.x,g0.y), a0[0]);
      a0[1]=fma2(mk2(da.z,da.w), mk2(g0.y,g0.y), a0[1]);
      a0[2]=fma2(mk2(db.x,db.y), mk2(g0.z,g0.z), a0[2]);
      a0[3]=fma2(mk2(db.z,db.w), mk2(g0.z,g0.w), a0[3]);
      a1[0]=fma2(mk2(da.x,da.y), mk2(g1.x,g1.y), a1[0]);
      a1[1]=fma2(mk2(da.z,da.w), mk2(g1.y,g1.y), a1[1]);
      a1[2]=fma2(mk2(db.x,db.y), mk2(g1.z,g1.z), a1[2]);
      a1[3]=fma2(mk2(db.z,db.w), mk2(g1.z,g1.w), a1[3]);
    }
    *(float4*)(Bv + e*ST + q*8)       = make_float4(a0[0].x,a0[0].y,a0[1].x,a0[1].y);
    *(float4*)(Bv + e*ST + q*8 + 4)   = make_float4(a0[2].x,a0[2].y,a0[3].x,a0[3].y);
    *(float4*)(Bv + e*ST + (q+8)*8)   = make_float4(a1[0].x,a1[0].y,a1[1].x,a1[1].y);
    *(float4*)(Bv + e*ST + (q+8)*8+4) = make_float4(a1[2].x,a1[2].y,a1[3].x,a1[3].y);
    v2f s0=mk2(0.f,0.f), s1=mk2(0.f,0.f);
    #pragma unroll
    for(int b=0;b<4;b++){ s0=fma2(a0[b],a0[b],s0); s1=fma2(a1[b],a1[b],s1); }
    sEP[e*16+q]=s0.x+s0.y; sEP[e*16+q+8]=s1.x+s1.y;
  }
  __syncthreads();

  // Ph3: h = relu(A[send] + B[rec] + ea@W1c + b1)   (packed over c pairs)
  {
    const int j = t&127, eg = t>>7;
    v2f w1c[8];
    #pragma unroll
    for(int c=0;c<8;c++) w1c[c]=mk2(W1c[(size_t)(2*c)*128 + j], W1c[(size_t)(2*c+1)*128 + j]);
    const float bb = b1[j];
    for(int ei=0; ei<16; ei++){
      const int e = eg*16 + ei;
      const float base = A[(size_t)sS[e]*128 + j] + Bn[(size_t)sR[e]*128 + j] + bb;
      v2f accv = mk2(0.f,0.f);
      const v2f* eap = (const v2f*)(sEP + e*16);
      #pragma unroll
      for(int c=0;c<8;c++) accv = fma2(eap[c], w1c[c], accv);
      B2[e*ST + j] = frelu(base + accv.x + accv.y);
    }
  }
  __syncthreads();

  // Ph4: m = h@W2 + b2 -> B0 (packed fp32; SORTED=0: also atomic scatter)
  {
    const int jq = t&31, eg = t>>5;
    const int j0 = jq*4;
    float4 bb = *(const float4*)(b2 + j0);
    v2f acc[4][2];
    #pragma unroll
    for(int a=0;a<4;a++){ acc[a][0]=mk2(bb.x,bb.y); acc[a][1]=mk2(bb.z,bb.w); }
    for(int k=0;k<128;k+=4){
      float4 w0=*(const float4*)(W2 + (size_t)(k+0)*128 + j0);
      float4 w1=*(const float4*)(W2 + (size_t)(k+1)*128 + j0);
      float4 w2=*(const float4*)(W2 + (size_t)(k+2)*128 + j0);
      float4 w3=*(const float4*)(W2 + (size_t)(k+3)*128 + j0);
      v2f w0a=mk2(w0.x,w0.y), w0b=mk2(w0.z,w0.w);
      v2f w1a=mk2(w1.x,w1.y), w1b=mk2(w1.z,w1.w);
      v2f w2a=mk2(w2.x,w2.y), w2b=mk2(w2.z,w2.w);
      v2f w3a=mk2(w3.x,w3.y), w3b=mk2(w3.z,w3.w);
      #pragma unroll
      for(int a=0;a<4;a++){
        float4 h4=*(const float4*)(B2 + (eg*4+a)*ST + k);
        v2f hx=mk2(h4.x,h4.x), hy=mk2(h4.y,h4.y), hz=mk2(h4.z,h4.z), hw=mk2(h4.w,h4.w);
        acc[a][0]=fma2(hx,w0a,acc[a][0]); acc[a][1]=fma2(hx,w0b,acc[a][1]);
        acc[a][0]=fma2(hy,w1a,acc[a][0]); acc[a][1]=fma2(hy,w1b,acc[a][1]);
        acc[a][0]=fma2(hz,w2a,acc[a][0]); acc[a][1]=fma2(hz,w2b,acc[a][1]);
        acc[a][0]=fma2(hw,w3a,acc[a][0]); acc[a][1]=fma2(hw,w3b,acc[a][1]);
      }
    }
    #pragma unroll
    for(int a=0;a<4;a++){
      const int e = eg*4+a;
      *(float4*)(B0 + e*ST + j0) = make_float4(acc[a][0].x,acc[a][0].y,acc[a][1].x,acc[a][1].y);
      if(!SORTED){
        float* mg = Magg + (size_t)sR[e]*128 + j0;
        atomicAdd(mg+0, acc[a][0].x); atomicAdd(mg+1, acc[a][0].y);
        atomicAdd(mg+2, acc[a][1].x); atomicAdd(mg+3, acc[a][1].y);
      }
    }
  }
  __syncthreads();

  // Ph5: q = relu(m@pW1 + pb1) -> B2 (packed fp32)
  {
    const int jq = t&31, eg = t>>5;
    const int j0 = jq*4;
    float4 bb = *(const float4*)(pb1 + j0);
    v2f acc[4][2];
    #pragma unroll
    for(int a=0;a<4;a++){ acc[a][0]=mk2(bb.x,bb.y); acc[a][1]=mk2(bb.z,bb.w); }
    for(int k=0;k<128;k+=4){
      float4 w0=*(const float4*)(pW1 + (size_t)(k+0)*128 + j0);
      float4 w1=*(const float4*)(pW1 + (size_t)(k+1)*128 + j0);
      float4 w2=*(const float4*)(pW1 + (size_t)(k+2)*128 + j0);
      float4 w3=*(const float4*)(pW1 + (size_t)(k+3)*128 + j0);
      v2f w0a=mk2(w0.x,w0.y), w0b=mk2(w0.z,w0.w);
      v2f w1a=mk2(w1.x,w1.y), w1b=mk2(w1.z,w1.w);
      v2f w2a=mk2(w2.x,w2.y), w2b=mk2(w2.z,w2.w);
      v2f w3a=mk2(w3.x,w3.y), w3b=mk2(w3.z,w3.w);
      #pragma unroll
      for(int a=0;a<4;a++){
        float4 m4=*(const float4*)(B0 + (eg*4+a)*ST + k);
        v2f hx=mk2(m4.x,m4.x), hy=mk2(m4.y,m4.y), hz=mk2(m4.z,m4.z), hw=mk2(m4.w,m4.w);
        acc[a][0]=fma2(hx,w0a,acc[a][0]); acc[a][1]=fma2(hx,w0b,acc[a][1]);
        acc[a][0]=fma2(hy,w1a,acc[a][0]); acc[a][1]=fma2(hy,w1b,acc[a][1]);
        acc[a][0]=fma2(hz,w2a,acc[a][0]); acc[a][1]=fma2(hz,w2b,acc[a][1]);
        acc[a][0]=fma2(hw,w3a,acc[a][0]); acc[a][1]=fma2(hw,w3b,acc[a][1]);
      }
    }
    #pragma unroll
    for(int a=0;a<4;a++){
      const int e = eg*4+a;
      *(float4*)(B2 + e*ST + j0) = make_float4(frelu(acc[a][0].x),frelu(acc[a][0].y),
                                               frelu(acc[a][1].x),frelu(acc[a][1].y));
    }
  }
  __syncthreads();

  // Ph6: pm = q@pW2 + pb2 -> sEP (packed: cols jq and jq+8 as lanes)
  {
    const int e = t>>3, jq = t&7;
    v2f acc = mk2(pb2[jq], pb2[jq+8]);
    const float* qp = B2 + e*ST;
    for(int k=0;k<128;k+=4){
      float4 q4 = *(const float4*)(qp + k);
      v2f wa=mk2(pW2[(k+0)*16+jq], pW2[(k+0)*16+jq+8]);
      v2f wb=mk2(pW2[(k+1)*16+jq], pW2[(k+1)*16+jq+8]);
      v2f wc=mk2(pW2[(k+2)*16+jq], pW2[(k+2)*16+jq+8]);
      v2f wd=mk2(pW2[(k+3)*16+jq], pW2[(k+3)*16+jq+8]);
      acc=fma2(mk2(q4.x,q4.x),wa,acc);
      acc=fma2(mk2(q4.y,q4.y),wb,acc);
      acc=fma2(mk2(q4.z,q4.z),wc,acc);
      acc=fma2(mk2(q4.w,q4.w),wd,acc);
    }
    sEP[e*16+jq]=acc.x; sEP[e*16+jq+8]=acc.y;
  }
  __syncthreads();

  // Ph7: pos_m = v_ij * pm -> B2 (SORTED=0: atomic scatter instead)
  {
    const int e = t>>3, q = t&7;
    #pragma unroll
    for(int i=0;i<4;i++){
      int f = q + i*8;
      float4 vv = *(const float4*)(Bv + e*ST + f*4);
      float pmv = sEP[e*16 + (f>>1)];
      if(SORTED){
        *(float4*)(B2 + e*ST + f*4) = make_float4(vv.x*pmv, vv.y*pmv, vv.z*pmv, vv.w*pmv);
      } else {
        float* pg = Pagg + (size_t)sR[e]*128;
        atomicAdd(pg + f*4 + 0, vv.x*pmv);
        atomicAdd(pg + f*4 + 1, vv.y*pmv);
        atomicAdd(pg + f*4 + 2, vv.z*pmv);
        atomicAdd(pg + f*4 + 3, vv.w*pmv);
      }
    }
  }

  // Ph8 (SORTED only): rec-segmented reduce -> one atomicAdd per (segment, column).
  if(SORTED){
    __syncthreads();
    const float* src = (t<128) ? B0 : B2;
    float* dst = (t<128) ? Magg : Pagg;
    const int j = t&127;
    float run = 0.f;
    int cr = sR[0];
    #pragma unroll 4
    for(int e=0;e<ET;e++){
      const int r = sR[e];
      if(r!=cr){
        atomicAdd(&dst[(size_t)cr*128 + j], run);
        run = 0.f; cr = r;
      }
      run += src[e*ST + j];
    }
    atomicAdd(&dst[(size_t)cr*128 + j], run);
  }
}

// ---------------- node kernel (reads pre-aggregated sums) ----------------
__global__ __launch_bounds__(256) void k_node(
    const float* __restrict__ s, const float* __restrict__ v,
    const float* __restrict__ uW1, const float* __restrict__ ub1,
    const float* __restrict__ uW2, const float* __restrict__ ub2,
    const float* __restrict__ glw, const float* __restrict__ glb,
    const float* __restrict__ grw, const float* __restrict__ grb,
    const float* __restrict__ gow, const float* __restrict__ gob,
    const float* __restrict__ lna,
    const float* __restrict__ mIn, const float* __restrict__ pIn,
    const int* __restrict__ degS,
    float* __restrict__ outS, float* __restrict__ outV)
{
  __shared__ float sX[16*256];
  __shared__ float sT[16*128];
  __shared__ float sP[16*128];
  __shared__ float sG[16*128];
  __shared__ float sNrm[256];
  __shared__ float sInv[16];
  const int t = threadIdx.x;
  const int nb = blockIdx.x*16;
  if(t<16) sInv[t] = rsqrtf((float)degS[nb+t]);
  __syncthreads();
  for(int i=t;i<16*256;i+=256){
    int n=i>>8, c=i&255;
    sX[i] = (c<128) ? s[(size_t)(nb+n)*128 + c]
                    : mIn[(size_t)(nb+n)*128 + (c-128)]*sInv[n];
  }
  for(int i=t;i<16*128;i+=256) sP[i] = pIn[(size_t)nb*128 + i]*sInv[i>>7];
  __syncthreads();
  // u1: relu(x@uW1+b1)  (packed over k pairs)
  {
    const int j = t&127, ng = t>>7;
    v2f acc[8]; const float bb=ub1[j];
    #pragma unroll
    for(int n=0;n<8;n++) acc[n]=mk2(bb,0.f);
    for(int k=0;k<256;k+=2){
      v2f w = mk2(uW1[(size_t)k*128+j], uW1[(size_t)(k+1)*128+j]);
      #pragma unroll
      for(int n=0;n<8;n++){
        v2f x = *(const v2f*)(sX + (ng*8+n)*256 + k);
        acc[n] = fma2(x, w, acc[n]);
      }
    }
    #pragma unroll
    for(int n=0;n<8;n++) sT[(ng*8+n)*128 + j] = frelu(acc[n].x + acc[n].y);
  }
  __syncthreads();
  // u2 + residual -> s_new  (packed over k pairs)
  {
    const int j = t&127, ng = t>>7;
    v2f acc[8]; const float bb=ub2[j];
    #pragma unroll
    for(int n=0;n<8;n++) acc[n]=mk2(bb,0.f);
    for(int k=0;k<128;k+=2){
      v2f w = mk2(uW2[(size_t)k*128+j], uW2[(size_t)(k+1)*128+j]);
      #pragma unroll
      for(int n=0;n<8;n++){
        v2f x = *(const v2f*)(sT + (ng*8+n)*128 + k);
        acc[n] = fma2(x, w, acc[n]);
      }
    }
    #pragma unroll
    for(int n=0;n<8;n++){
      const size_t r = (size_t)(nb + ng*8 + n)*128 + j;
      outS[r] = s[r] + acc[n].x + acc[n].y;
    }
  }
  float vo[8];
  {
    const int n = t>>4, o = t&15;
    float vl[8], vr[8];
    #pragma unroll
    for(int b=0;b<8;b++){vl[b]=0.f; vr[b]=0.f;}
    vl[0]=glb[o]; vr[0]=grb[o];
    #pragma unroll
    for(int c=0;c<16;c++){
      float4 pa=*(const float4*)(sP + n*128 + c*8);
      float4 pb=*(const float4*)(sP + n*128 + c*8 + 4);
      float4 ga=*(const float4*)(glw + (o*16+c)*4);
      float4 gb=*(const float4*)(grw + (o*16+c)*4);
      vl[0]+=pa.x*ga.x; vl[1]+=pa.y*ga.y; vl[2]+=pa.z*ga.y; vl[3]+=pa.w*ga.y;
      vl[4]+=pb.x*ga.z; vl[5]+=pb.y*ga.z; vl[6]+=pb.z*ga.z; vl[7]+=pb.w*ga.w;
      vr[0]+=pa.x*gb.x; vr[1]+=pa.y*gb.y; vr[2]+=pa.z*gb.y; vr[3]+=pa.w*gb.y;
      vr[4]+=pb.x*gb.z; vr[5]+=pb.y*gb.z; vr[6]+=pb.z*gb.z; vr[7]+=pb.w*gb.w;
    }
    float g[8];
    #pragma unroll
    for(int b=0;b<8;b++) g[b]=0.f;
    const int MASKS[8]={0,1,2,4,3,5,6,7};
    #pragma unroll
    for(int i=0;i<8;i++){
      #pragma unroll
      for(int jj=0;jj<8;jj++){
        const int a=MASKS[i], b=MASKS[jj];
        const int kk=MASKS[a^b];
        int sg=1;
        for(int tt=a>>1; tt; tt>>=1) if(__popc(tt&b)&1) sg=-sg;
        const float pr = vl[i]*vr[jj];
        g[kk] += (sg>0)? pr : -pr;
      }
    }
    *(float4*)(sG + n*128 + o*8)     = make_float4(g[0],g[1],g[2],g[3]);
    *(float4*)(sG + n*128 + o*8 + 4) = make_float4(g[4],g[5],g[6],g[7]);
  }
  __syncthreads();
  {
    const int n = t>>4, o = t&15;
    #pragma unroll
    for(int b=0;b<8;b++) vo[b]=0.f;
    vo[0]=gob[o];
    #pragma unroll
    for(int c=0;c<32;c++){
      const float* src = (c<16) ? (sG + n*128 + c*8) : (sP + n*128 + (c-16)*8);
      float4 sa=*(const float4*)(src);
      float4 sb=*(const float4*)(src+4);
      float4 gw=*(const float4*)(gow + (o*32+c)*4);
      vo[0]+=sa.x*gw.x; vo[1]+=sa.y*gw.y; vo[2]+=sa.z*gw.y; vo[3]+=sa.w*gw.y;
      vo[4]+=sb.x*gw.z; vo[5]+=sb.y*gw.z; vo[6]+=sb.z*gw.z; vo[7]+=sb.w*gw.w;
    }
    float ssum=0.f;
    #pragma unroll
    for(int b=0;b<8;b++) ssum+=vo[b]*vo[b];
    sNrm[t]=sqrtf(ssum);
  }
  __syncthreads();
  {
    const int n = t>>4, o = t&15;
    float mn=0.f;
    #pragma unroll
    for(int c=0;c<16;c++) mn += sNrm[n*16+c];
    mn = mn*(1.f/16.f) + 1e-6f;
    const float sc = lna[o]/mn;
    const size_t base = (size_t)(nb+n)*128 + o*8;
    float4 v0=*(const float4*)(v+base);
    float4 v1=*(const float4*)(v+base+4);
    *(float4*)(outV+base)   = make_float4(vo[0]*sc+v0.x, vo[1]*sc+v0.y, vo[2]*sc+v0.z, vo[3]*sc+v0.w);
    *(float4*)(outV+base+4) = make_float4(vo[4]*sc+v1.x, vo[5]*sc+v1.y, vo[6]*sc+v1.z, vo[7]*sc+v1.w);
  }
}

extern "C" void kernel_launch(void* const* d_in, const int* in_sizes, int n_in,
                              void* d_out, int out_size, void* d_ws, size_t ws_size,
                              hipStream_t stream){
  (void)in_sizes; (void)n_in; (void)out_size;
  const float* s    = (const float*)d_in[0];
  const float* v    = (const float*)d_in[1];
  const int*   eidx = (const int*)d_in[2];
  const float* Wvw  = (const float*)d_in[3];
  const float* Wvb  = (const float*)d_in[4];
  const float* mnW1 = (const float*)d_in[5];
  const float* mnb1 = (const float*)d_in[6];
  const float* mnW2 = (const float*)d_in[7];
  const float* mnb2 = (const float*)d_in[8];
  const float* pnW1 = (const float*)d_in[9];
  const float* pnb1 = (const float*)d_in[10];
  const float* pnW2 = (const float*)d_in[11];
  const float* pnb2 = (const float*)d_in[12];
  const float* unW1 = (const float*)d_in[13];
  const float* unb1 = (const float*)d_in[14];
  const float* unW2 = (const float*)d_in[15];
  const float* unb2 = (const float*)d_in[16];
  const float* glw  = (const float*)d_in[17];
  const float* glb  = (const float*)d_in[18];
  const float* grw  = (const float*)d_in[19];
  const float* grb  = (const float*)d_in[20];
  const float* gow  = (const float*)d_in[21];
  const float* gob  = (const float*)d_in[22];
  const float* lna  = (const float*)d_in[23];

  float* outS = (float*)d_out;
  float* outV = outS + (size_t)NN*128;
  float* A    = outS;            // A/Bn stage in d_out (dead until k_node writes)
  float* Bn   = outV;

  const size_t need = ((size_t)2*NN*128)*sizeof(float) + ((size_t)3*NN + NE)*sizeof(int);

  float* Magg = (float*)d_ws;
  float* Pagg = Magg + (size_t)NN*128;
  int* degS = (int*)(Pagg + (size_t)NN*128);
  int* cntR = degS + NN;
  int* cur  = cntR + NN;
  int* eord = cur + NN;

  if(ws_size >= need){
    (void)hipMemsetAsync(Magg, 0, (size_t)2*NN*128*sizeof(float) + (size_t)2*NN*sizeof(int), stream);
    k_hist<<<(NE+255)/256, 256, 0, stream>>>(eidx, degS, cntR, 1);
    k_scan<<<1, 256, 0, stream>>>(cntR, cur);
    k_fill<<<(NE+255)/256, 256, 0, stream>>>(eidx, cur, eord);
    k_ab<<<NN/8, 256, 0, stream>>>(s, mnW1, A, Bn);
    k_edge<1><<<NE/ET, 256, 0, stream>>>(v, eidx, Wvw, Wvb, mnW1 + 256*128, mnb1,
                                         mnW2, mnb2, pnW1, pnb1, pnW2, pnb2,
                                         A, Bn, eord, Magg, Pagg);
    k_node<<<NN/16, 256, 0, stream>>>(s, v, unW1, unb1, unW2, unb2,
                                      glw, glb, grw, grb, gow, gob, lna,
                                      Magg, Pagg, degS, outS, outV);
  } else {
    (void)hipMemsetAsync(Magg, 0, (size_t)2*NN*128*sizeof(float) + (size_t)NN*sizeof(int), stream);
    k_hist<<<(NE+255)/256, 256, 0, stream>>>(eidx, degS, (int*)0, 0);
    k_ab<<<NN/8, 256, 0, stream>>>(s, mnW1, A, Bn);
    k_edge<0><<<NE/ET, 256, 0, stream>>>(v, eidx, Wvw, Wvb, mnW1 + 256*128, mnb1,
                                         mnW2, mnb2, pnW1, pnb1, pnW2, pnb2,
                                         A, Bn, (int*)0, Magg, Pagg);
    k_node<<<NN/16, 256, 0, stream>>>(s, v, unW1, unb1, unW2, unb2,
                                      glw, glb, grw, grb, gow, gob, lna,
                                      Magg, Pagg, degS, outS, outV);
  }
}